// Round 5
// baseline (554.615 us; speedup 1.0000x reference)
//
#include <hip/hip_runtime.h>
#include <stdint.h>

#define M_DIM 8192
#define N_DIM 4096
#define K_DIM 4096

typedef __attribute__((ext_vector_type(4)))  float  floatx4;
typedef __attribute__((ext_vector_type(16))) float  floatx16;
typedef __attribute__((ext_vector_type(4)))  unsigned int uintx4;
typedef __attribute__((ext_vector_type(8)))  _Float16 halfx8;

// ---------------------------------------------------------------------------
// Merged conversion kernel: A (fp32->f16) and W (fp32 * group-scale -> f16).
// NT loads: fp32 sources are dead after this kernel — don't pollute L2/L3.
// ---------------------------------------------------------------------------

#define A_CHUNKS (M_DIM * K_DIM / 8)
#define W_CHUNKS (N_DIM * K_DIM / 8)
#define A_BLOCKS (A_CHUNKS / 256)      // 16384
#define W_BLOCKS (W_CHUNKS / 256)      // 8192

__global__ __launch_bounds__(256) void cvt_all(const float* __restrict__ a_in,
                                               const float* __restrict__ w_in,
                                               const float* __restrict__ scales,
                                               _Float16* __restrict__ a16,
                                               _Float16* __restrict__ w16) {
    const int b = blockIdx.x;
    if (b < A_BLOCKS) {
        const int t = b * 256 + threadIdx.x;
        const floatx4* in4 = (const floatx4*)a_in;
        floatx4 x = __builtin_nontemporal_load(&in4[2 * t]);
        floatx4 y = __builtin_nontemporal_load(&in4[2 * t + 1]);
        union { _Float16 h[8]; uintx4 u; } p;
        p.h[0] = (_Float16)x[0]; p.h[1] = (_Float16)x[1];
        p.h[2] = (_Float16)x[2]; p.h[3] = (_Float16)x[3];
        p.h[4] = (_Float16)y[0]; p.h[5] = (_Float16)y[1];
        p.h[6] = (_Float16)y[2]; p.h[7] = (_Float16)y[3];
        ((uintx4*)a16)[t] = p.u;
    } else {
        const int t = (b - A_BLOCKS) * 256 + threadIdx.x;
        const int o = t >> 9;
        const int k = (t & 511) * 8;
        const float s = scales[(k >> 7) * N_DIM + o];
        const floatx4* w4 = (const floatx4*)w_in;
        floatx4 x = __builtin_nontemporal_load(&w4[2 * t]);
        floatx4 y = __builtin_nontemporal_load(&w4[2 * t + 1]);
        union { _Float16 h[8]; uintx4 u; } p;
        p.h[0] = (_Float16)(x[0] * s); p.h[1] = (_Float16)(x[1] * s);
        p.h[2] = (_Float16)(x[2] * s); p.h[3] = (_Float16)(x[3] * s);
        p.h[4] = (_Float16)(y[0] * s); p.h[5] = (_Float16)(y[1] * s);
        p.h[6] = (_Float16)(y[2] * s); p.h[7] = (_Float16)(y[3] * s);
        ((uintx4*)w16)[t] = p.u;
    }
}

// ---------------------------------------------------------------------------
// f16 GEMM: block tile 256x128, BK=64, 4 waves in 2x2, wave tile 128x64
// (4x2 frags of 32x32x16). Wave tile growth cuts LDS-read demand per FLOP:
// (WM+WN)/(WM*WN) = 1/42.7 B/FLOP -> 384 B/clk demand vs 256 supply ->
// MfmaUtil cap 67% (was 50% at 64x64 waves; measured 46%).
// C[m,n] = sum_k A[m,k]*B[n,k] + bias[n]
// ---------------------------------------------------------------------------

__device__ __forceinline__ void gld_lds16(const _Float16* g, _Float16* l) {
    __builtin_amdgcn_global_load_lds(
        (const __attribute__((address_space(1))) void*)g,
        (__attribute__((address_space(3))) void*)l,
        16, 0, 0);
}

__global__ __launch_bounds__(256, 2) void gemm_f16(const _Float16* __restrict__ A,
                                                   const _Float16* __restrict__ B,
                                                   const float* __restrict__ bias,
                                                   float* __restrict__ C) {
    __shared__ _Float16 sA[256 * 64];   // 32 KiB; LDS slot s of row r holds
    __shared__ _Float16 sB[128 * 64];   // 16 KiB; global k-chunk s ^ (r&7)

    const int tid   = threadIdx.x;
    const int wave  = tid >> 6;
    const int lane  = tid & 63;
    const int l32   = lane & 31;
    const int khalf = lane >> 5;        // which 8-wide half of the 16-wide k-step

    const int m0 = blockIdx.y * 256;
    const int n0 = blockIdx.x * 128;
    const int wm = (wave >> 1) * 128;   // wave tile: 128 (m) x 64 (n)
    const int wn = (wave & 1) * 64;

    // Staging: issue q covers chunk c = q*256 + tid.
    // row = c>>3 = q*32 + (tid>>3); LDS slot = tid&7; global chunk = slot ^ (row&7).
    // row&7 == (tid>>3)&7 for every q -> one offset for all issues.
    const int rbase = tid >> 3;                               // 0..31
    const int g8    = ((tid & 7) ^ ((tid >> 3) & 7)) * 8;     // k-offset in halves
    const size_t offG = (size_t)rbase * K_DIM + g8;

    const _Float16* Ab = A + (size_t)m0 * K_DIM;
    const _Float16* Bb = B + (size_t)n0 * K_DIM;

    // Wave-uniform LDS bases (HW adds lane*16 bytes)
    _Float16* ldsA[8];
    _Float16* ldsB[4];
#pragma unroll
    for (int q = 0; q < 8; ++q) ldsA[q] = &sA[(q * 256 + wave * 64) * 8];
#pragma unroll
    for (int q = 0; q < 4; ++q) ldsB[q] = &sB[(q * 256 + wave * 64) * 8];

    floatx16 acc[4][2] = {};

    for (int k0 = 0; k0 < K_DIM; k0 += 64) {
#pragma unroll
        for (int q = 0; q < 8; ++q)
            gld_lds16(Ab + offG + (size_t)q * 32 * K_DIM + k0, ldsA[q]);
#pragma unroll
        for (int q = 0; q < 4; ++q)
            gld_lds16(Bb + offG + (size_t)q * 32 * K_DIM + k0, ldsB[q]);
        __syncthreads();

#pragma unroll
        for (int t = 0; t < 4; ++t) {            // 4 k-steps of 16
            const int slot = ((t * 2 + khalf) ^ (l32 & 7)) * 8;
            halfx8 a_frag[4], b_frag[2];
#pragma unroll
            for (int i = 0; i < 4; ++i)
                a_frag[i] = *(const halfx8*)&sA[(wm + i * 32 + l32) * 64 + slot];
#pragma unroll
            for (int j = 0; j < 2; ++j)
                b_frag[j] = *(const halfx8*)&sB[(wn + j * 32 + l32) * 64 + slot];
#pragma unroll
            for (int i = 0; i < 4; ++i)
#pragma unroll
                for (int j = 0; j < 2; ++j)
                    acc[i][j] = __builtin_amdgcn_mfma_f32_32x32x16_f16(
                        a_frag[i], b_frag[j], acc[i][j], 0, 0, 0);
        }
        __syncthreads();
    }

    // Epilogue: 32x32 C/D layout col = lane&31, row = (r&3) + 8*(r>>2) + 4*(lane>>5)
#pragma unroll
    for (int i = 0; i < 4; ++i) {
#pragma unroll
        for (int j = 0; j < 2; ++j) {
            const int n = n0 + wn + j * 32 + l32;
            const float bv = bias[n];
#pragma unroll
            for (int r = 0; r < 16; ++r) {
                const int m = m0 + wm + i * 32 + (r & 3) + 8 * (r >> 2) + 4 * khalf;
                C[(size_t)m * N_DIM + n] = acc[i][j][r] + bv;
            }
        }
    }
}

// ---------------------------------------------------------------------------
// Exact fp32 fallback (only if workspace is too small) — slow but correct.
// ---------------------------------------------------------------------------

__global__ __launch_bounds__(256) void fallback_gemm(const float* __restrict__ A,
                                                     const float* __restrict__ W,
                                                     const float* __restrict__ S,
                                                     const float* __restrict__ bias,
                                                     float* __restrict__ C) {
    const long idx = (long)blockIdx.x * 256 + threadIdx.x;
    const int m = (int)(idx >> 12);
    const int n = (int)(idx & 4095);
    const float* a = A + (size_t)m * K_DIM;
    const float* w = W + (size_t)n * K_DIM;
    float acc = 0.f;
    for (int g = 0; g < 32; ++g) {
        const float s = S[g * N_DIM + n];
        float part = 0.f;
        const int kb = g * 128;
#pragma unroll 4
        for (int k = kb; k < kb + 128; ++k) part += a[k] * w[k];
        acc += part * s;
    }
    C[idx] = acc + bias[n];
}

// ---------------------------------------------------------------------------

extern "C" void kernel_launch(void* const* d_in, const int* in_sizes, int n_in,
                              void* d_out, int out_size, void* d_ws, size_t ws_size,
                              hipStream_t stream) {
    const float* input   = (const float*)d_in[0];
    const float* qweight = (const float*)d_in[1];
    const float* scales  = (const float*)d_in[2];
    const float* bias    = (const float*)d_in[3];
    float* out = (float*)d_out;

    const size_t a_bytes = (size_t)M_DIM * K_DIM * sizeof(_Float16); // 64 MiB
    const size_t w_bytes = (size_t)N_DIM * K_DIM * sizeof(_Float16); // 32 MiB

    if (ws_size >= a_bytes + w_bytes) {
        _Float16* a16 = (_Float16*)d_ws;
        _Float16* w16 = (_Float16*)((char*)d_ws + a_bytes);

        cvt_all<<<A_BLOCKS + W_BLOCKS, 256, 0, stream>>>(input, qweight, scales, a16, w16);

        dim3 grid(N_DIM / 128, M_DIM / 256);   // (32, 32)
        gemm_f16<<<grid, 256, 0, stream>>>(a16, w16, bias, out);
    } else {
        fallback_gemm<<<((size_t)M_DIM * N_DIM) / 256, 256, 0, stream>>>(
            input, qweight, scales, bias, out);
    }
}